// Round 4
// baseline (241.647 us; speedup 1.0000x reference)
//
#include <hip/hip_runtime.h>

// Causal linear attention (elu+1 feature map) — chunked MFMA formulation.
// N=4, L=4096, H=12, D=M=64. Per chunk of C=64 (all matmuls bf16 MFMA, fp32 acc):
//   A = Qf Kf^T (causal-masked);  O = Amask V + Qf S_prefix
//   z = rowsum(Amask) + Qf Ksum_prefix
// Pipeline: k_sum (per-chunk KV^T sums, bf16 frag-packed ws) ->
//           k_gscan (group-hierarchical exclusive scan, independent loads) ->
//           k_out (A/B/C MFMA phases; S_prefix = group prefix + intra-group sums).

#define NBATCH 4
#define LSEQ   4096
#define NHEAD  12
#define DDIM   64
#define LSTRIDE (NHEAD * DDIM)
#define NH     (NBATCH * NHEAD)
#define EPSF   1e-6f
#define CHUNK  64
#define NUMC   (LSEQ / CHUNK)   // 64
#define GRP    8
#define NGRP   (NUMC / GRP)     // 8
#define SB     72               // padded LDS row stride (shorts) for row-major tiles

typedef __attribute__((ext_vector_type(8))) short bf16x8;
typedef __attribute__((ext_vector_type(4))) float f32x4;

__device__ __forceinline__ float phi(float x) { return x > 0.f ? x + 1.f : __expf(x); }

__device__ __forceinline__ unsigned short f2bf(float x) {
    union { float f; unsigned u; } v; v.f = x;
    unsigned r = v.u + 0x7fffu + ((v.u >> 16) & 1u);   // RNE
    return (unsigned short)(r >> 16);
}
__device__ __forceinline__ float bf2f(short s) {
    union { float f; unsigned u; } v; v.u = ((unsigned)(unsigned short)s) << 16;
    return v.f;
}
__device__ __forceinline__ uint2 pack4(float4 a) {
    uint2 r;
    r.x = (unsigned)f2bf(a.x) | ((unsigned)f2bf(a.y) << 16);
    r.y = (unsigned)f2bf(a.z) | ((unsigned)f2bf(a.w) << 16);
    return r;
}
__device__ __forceinline__ uint2 pack4v(f32x4 a) {
    float4 t = {a[0], a[1], a[2], a[3]};
    return pack4(t);
}
__device__ __forceinline__ float4 unpack4(uint2 p) {
    float4 a;
    a.x = __uint_as_float(p.x << 16);
    a.y = __uint_as_float(p.x & 0xffff0000u);
    a.z = __uint_as_float(p.y << 16);
    a.w = __uint_as_float(p.y & 0xffff0000u);
    return a;
}

// XOR-swizzled offset (in shorts) into an unpadded 64x64 bf16 tile.
// u = 16B-unit index (0..7) along the row. Conflict-free for both the
// transposed staging writes and the 16B frag reads.
__device__ __forceinline__ int swz_off(int row, int u) {
    return row * 64 + (((u ^ (row ^ (row >> 3))) & 7) << 3);
}

// 4x4 fp32 transpose among lanes {lane^16, lane^32}.
__device__ __forceinline__ float4 xpose4(float4 x, int lane) {
    const bool b0 = (lane >> 4) & 1, b1 = (lane >> 5) & 1;
    float s0 = b0 ? x.x : x.y;
    float s1 = b0 ? x.z : x.w;
    s0 = __shfl_xor(s0, 16);
    s1 = __shfl_xor(s1, 16);
    float4 y;
    if (b0) { y.x = s0;  y.y = x.y; y.z = s1;  y.w = x.w; }
    else    { y.x = x.x; y.y = s0;  y.z = x.z; y.w = s1;  }
    float t0 = b1 ? y.x : y.z;
    float t1 = b1 ? y.y : y.w;
    t0 = __shfl_xor(t0, 32);
    t1 = __shfl_xor(t1, 32);
    float4 z;
    if (b1) { z.x = t0;  z.y = t1;  z.z = y.z; z.w = y.w; }
    else    { z.x = y.x; z.y = y.y; z.z = t0;  z.w = t1;  }
    return z;
}

// ---------------------------------------------------------------------------
// Kernel 1: per-chunk KV^T[m][d] = sum_l V[l][m] Kf[l][d];  Ksum[d].
// Output: bf16 frag-packed uint2 at [b][w][ct][lane] (coalesced 8B stores).
//   acc[r] = KV^T[16w+4qq+r][16ct+nn]  packed as (r0,r1|r2,r3).
// ---------------------------------------------------------------------------
__global__ __launch_bounds__(256, 4) void k_sum_mf(const float* __restrict__ kin,
                                                   const float* __restrict__ vin,
                                                   unsigned short* __restrict__ kv16,
                                                   float* __restrict__ ksws) {
    __shared__ short sKT[64 * 64];   // [d][l] swizzled
    __shared__ short sVT[64 * 64];   // [m][l] swizzled
    const int b = blockIdx.x, seq = b / NUMC, c = b % NUMC;
    const int n0 = seq / NHEAD, h0 = seq % NHEAD;
    const int t = threadIdx.x;
    const int gbase = ((n0 * LSEQ + c * CHUNK) * NHEAD + h0) * DDIM;
    const int lane = t & 63, w = t >> 6;
    const int nn = lane & 15, qq = lane >> 4;
    const int u0 = 2 * 0 + (w >> 1);         // unit base for rep loop (updated below)
    const int half = w & 1;

#pragma unroll
    for (int rep = 0; rep < 4; ++rep) {
        const int row = rep * 16 + 4 * w + qq;   // l
        const int c4 = nn << 2;
        const int urep = 2 * rep + (w >> 1);
        float4 kk = *(const float4*)(kin + gbase + row * LSTRIDE + c4);
        float4 kp = {phi(kk.x), phi(kk.y), phi(kk.z), phi(kk.w)};
        float4 kt = xpose4(kp, lane);            // lane now holds d-row 4nn+qq
        const int trow = 4 * nn + qq;
        *(uint2*)(sKT + swz_off(trow, urep) + (half << 2)) = pack4(kt);
        float4 vv = *(const float4*)(vin + gbase + row * LSTRIDE + c4);
        float4 vt = xpose4(vv, lane);
        *(uint2*)(sVT + swz_off(trow, urep) + (half << 2)) = pack4(vt);
    }
    (void)u0;
    __syncthreads();

    const int rowM = 16 * w + nn;    // m band of this wave
    bf16x8 af0 = *(const bf16x8*)(sVT + swz_off(rowM, qq));
    bf16x8 af1 = *(const bf16x8*)(sVT + swz_off(rowM, qq + 4));
    uint2* kvu = (uint2*)kv16 + (size_t)b * 1024;
    float ks = 0.f;

#pragma unroll
    for (int ct = 0; ct < 4; ++ct) {
        const int rowD = 16 * ct + nn;
        bf16x8 bf0 = *(const bf16x8*)(sKT + swz_off(rowD, qq));
        bf16x8 bf1 = *(const bf16x8*)(sKT + swz_off(rowD, qq + 4));
        f32x4 acc = {0.f, 0.f, 0.f, 0.f};
        acc = __builtin_amdgcn_mfma_f32_16x16x32_bf16(af0, bf0, acc, 0, 0, 0);
        acc = __builtin_amdgcn_mfma_f32_16x16x32_bf16(af1, bf1, acc, 0, 0, 0);
        if (ct == w) {   // Ksum for d-band 16w..16w+15 (wave-uniform branch)
            float s = 0.f;
#pragma unroll
            for (int j = 0; j < 8; ++j) s += bf2f(bf0[j]) + bf2f(bf1[j]);
            s += __shfl_xor(s, 16);
            s += __shfl_xor(s, 32);
            ks = s;
        }
        kvu[w * 256 + ct * 64 + lane] = pack4v(acc);   // coalesced 8B store
    }
    if (qq == 0) ksws[b * DDIM + 16 * w + nn] = ks;
}

// ---------------------------------------------------------------------------
// Kernel 2: group-hierarchical exclusive scan. Thread owns one uint2 column;
// all 64 chunk loads are independent (latency fully overlapped). Emits
// NGRP group-exclusive prefixes (bf16) + same for ksum (fp32).
// ---------------------------------------------------------------------------
__global__ __launch_bounds__(64) void k_gscan(const unsigned short* __restrict__ kv16,
                                              unsigned short* __restrict__ gp16,
                                              const float* __restrict__ ksws,
                                              float* __restrict__ gksws) {
    const int bid = blockIdx.x;
    const int seq = bid >> 4, part = bid & 15;
    const int t = threadIdx.x;
    const int col = part * 64 + t;                 // 0..1023
    const uint2* kvc = (const uint2*)kv16 + (size_t)seq * NUMC * 1024 + col;
    uint2* gpc = (uint2*)gp16 + (size_t)seq * NGRP * 1024 + col;
    float4 carry = {0.f, 0.f, 0.f, 0.f};
    for (int g = 0; g < NGRP; ++g) {
        uint2 x[GRP];
#pragma unroll
        for (int j = 0; j < GRP; ++j) x[j] = kvc[(g * GRP + j) * 1024];
        gpc[g * 1024] = pack4(carry);              // exclusive
#pragma unroll
        for (int j = 0; j < GRP; ++j) {
            float4 f = unpack4(x[j]);
            carry.x += f.x; carry.y += f.y; carry.z += f.z; carry.w += f.w;
        }
    }
    if (part == 0) {                               // ksum column t
        float ck = 0.f;
        const float* kc = ksws + (size_t)seq * NUMC * 64 + t;
        float* gk = gksws + (size_t)seq * NGRP * 64 + t;
        for (int g = 0; g < NGRP; ++g) {
            float x[GRP];
#pragma unroll
            for (int j = 0; j < GRP; ++j) x[j] = kc[(g * GRP + j) * 64];
            gk[g * 64] = ck;
#pragma unroll
            for (int j = 0; j < GRP; ++j) ck += x[j];
        }
    }
}

// ---------------------------------------------------------------------------
// Kernel 3: per-chunk output. S_prefix = group prefix + intra-group chunk sums.
// Phase A: A = Qf Kf^T (mask + rowsum). Phases B+C: O = Amask V + Qf S.
// ---------------------------------------------------------------------------
__global__ __launch_bounds__(256, 4) void k_out_mf(const float* __restrict__ qin,
                                                   const float* __restrict__ kin,
                                                   const float* __restrict__ vin,
                                                   const unsigned short* __restrict__ kv16,
                                                   const unsigned short* __restrict__ gp16,
                                                   const float* __restrict__ ksws,
                                                   const float* __restrict__ gksws,
                                                   float* __restrict__ out) {
    __shared__ short sQ [64 * SB];   // [i][d]
    __shared__ short sKA[64 * SB];   // [j][d] -> reused as Amask [i][l]
    __shared__ short sVT[64 * 64];   // [m][l] swizzled
    __shared__ short sST[64 * SB];   // [m][d]  (S^T)
    __shared__ float sKs[64];
    __shared__ float sZq[64];

    const int b = blockIdx.x, seq = b / NUMC, c = b % NUMC;
    const int n0 = seq / NHEAD, h0 = seq % NHEAD;
    const int g = c >> 3, r8 = c & 7;
    const int bg0 = seq * NUMC + (g << 3);         // first chunk-block of group
    const int t = threadIdx.x;
    const int gbase = ((n0 * LSEQ + c * CHUNK) * NHEAD + h0) * DDIM;
    const int lane = t & 63, w = t >> 6;
    const int nn = lane & 15, qq = lane >> 4;

    // normalizer prefix: sKs[d] = gksum + intra-group chunk ksums
    if (t < 64) {
        float s = gksws[(seq * NGRP + g) * 64 + t];
        for (int j = 0; j < r8; ++j) s += ksws[(bg0 + j) * 64 + t];
        sKs[t] = s;
    }

    // S^T staging: frag-packed group prefix + intra-group chunk sums (fp32 acc)
    {
        const uint2* kvu = (const uint2*)kv16;
        const uint2* gpu = (const uint2*)gp16 + ((size_t)seq * NGRP + g) * 1024;
#pragma unroll
        for (int ct = 0; ct < 4; ++ct) {
            const int inner = w * 256 + ct * 64 + lane;
            float4 a = unpack4(gpu[inner]);
            for (int j = 0; j < r8; ++j) {
                float4 f = unpack4(kvu[(size_t)(bg0 + j) * 1024 + inner]);
                a.x += f.x; a.y += f.y; a.z += f.z; a.w += f.w;
            }
            const int m0 = 16 * w + 4 * qq, dcol = 16 * ct + nn;
            sST[(m0 + 0) * SB + dcol] = (short)f2bf(a.x);
            sST[(m0 + 1) * SB + dcol] = (short)f2bf(a.y);
            sST[(m0 + 2) * SB + dcol] = (short)f2bf(a.z);
            sST[(m0 + 3) * SB + dcol] = (short)f2bf(a.w);
        }
    }

#pragma unroll
    for (int rep = 0; rep < 4; ++rep) {
        const int row = rep * 16 + 4 * w + qq;
        const int c4 = nn << 2;
        const int urep = 2 * rep + (w >> 1);
        const int half = w & 1;
        float4 qv = *(const float4*)(qin + gbase + row * LSTRIDE + c4);
        float4 kk = *(const float4*)(kin + gbase + row * LSTRIDE + c4);
        float4 qp = {phi(qv.x), phi(qv.y), phi(qv.z), phi(qv.w)};
        float4 kp = {phi(kk.x), phi(kk.y), phi(kk.z), phi(kk.w)};
        *(uint2*)(sQ  + row * SB + c4) = pack4(qp);
        *(uint2*)(sKA + row * SB + c4) = pack4(kp);
        float4 vv = *(const float4*)(vin + gbase + row * LSTRIDE + c4);
        float4 vt = xpose4(vv, lane);
        *(uint2*)(sVT + swz_off(4 * nn + qq, urep) + (half << 2)) = pack4(vt);
    }
    __syncthreads();

    // ---- Phase A ----
    const int rowA = 16 * w + nn;
    bf16x8 qf0 = *(const bf16x8*)(sQ + rowA * SB + qq * 8);
    bf16x8 qf1 = *(const bf16x8*)(sQ + rowA * SB + 32 + qq * 8);
    float am[4][4];
    float zrow[4] = {0.f, 0.f, 0.f, 0.f};
#pragma unroll
    for (int ct = 0; ct < 4; ++ct) {
        bf16x8 kf0 = *(const bf16x8*)(sKA + (16 * ct + nn) * SB + qq * 8);
        bf16x8 kf1 = *(const bf16x8*)(sKA + (16 * ct + nn) * SB + 32 + qq * 8);
        f32x4 acc = {0.f, 0.f, 0.f, 0.f};
        acc = __builtin_amdgcn_mfma_f32_16x16x32_bf16(qf0, kf0, acc, 0, 0, 0);
        acc = __builtin_amdgcn_mfma_f32_16x16x32_bf16(qf1, kf1, acc, 0, 0, 0);
#pragma unroll
        for (int r = 0; r < 4; ++r) {
            const int ri = 16 * w + 4 * qq + r, cj = 16 * ct + nn;
            const float mval = (cj <= ri) ? acc[r] : 0.f;
            am[ct][r] = mval;
            zrow[r] += mval;
        }
    }
#pragma unroll
    for (int r = 0; r < 4; ++r) {
        float s = zrow[r];
        s += __shfl_xor(s, 1); s += __shfl_xor(s, 2);
        s += __shfl_xor(s, 4); s += __shfl_xor(s, 8);
        zrow[r] = s;
    }
    float zq = 0.f;                  // Qf . Ksum_prefix for row 16w+nn
#pragma unroll
    for (int j = 0; j < 8; ++j) {
        zq += bf2f(qf0[j]) * sKs[qq * 8 + j];
        zq += bf2f(qf1[j]) * sKs[32 + qq * 8 + j];
    }
    zq += __shfl_xor(zq, 16);
    zq += __shfl_xor(zq, 32);

    __syncthreads();                 // done reading sKA as K
    if (qq == 0) sZq[16 * w + nn] = zq;
#pragma unroll
    for (int ct = 0; ct < 4; ++ct)
#pragma unroll
        for (int r = 0; r < 4; ++r)
            sKA[(16 * w + 4 * qq + r) * SB + 16 * ct + nn] = (short)f2bf(am[ct][r]);
    __syncthreads();

    // ---- Phases B + C ----
    f32x4 o[4] = {{0,0,0,0},{0,0,0,0},{0,0,0,0},{0,0,0,0}};
    bf16x8 af0 = *(const bf16x8*)(sKA + rowA * SB + qq * 8);
    bf16x8 af1 = *(const bf16x8*)(sKA + rowA * SB + 32 + qq * 8);
#pragma unroll
    for (int ct = 0; ct < 4; ++ct) {
        const int rowT = 16 * ct + nn;
        bf16x8 vf0 = *(const bf16x8*)(sVT + swz_off(rowT, qq));
        bf16x8 vf1 = *(const bf16x8*)(sVT + swz_off(rowT, qq + 4));
        o[ct] = __builtin_amdgcn_mfma_f32_16x16x32_bf16(af0, vf0, o[ct], 0, 0, 0);
        o[ct] = __builtin_amdgcn_mfma_f32_16x16x32_bf16(af1, vf1, o[ct], 0, 0, 0);
        bf16x8 sf0 = *(const bf16x8*)(sST + rowT * SB + qq * 8);
        bf16x8 sf1 = *(const bf16x8*)(sST + rowT * SB + 32 + qq * 8);
        o[ct] = __builtin_amdgcn_mfma_f32_16x16x32_bf16(qf0, sf0, o[ct], 0, 0, 0);
        o[ct] = __builtin_amdgcn_mfma_f32_16x16x32_bf16(qf1, sf1, o[ct], 0, 0, 0);
    }

#pragma unroll
    for (int r = 0; r < 4; ++r) {
        const int ri = 16 * w + 4 * qq + r;
        const float z = zrow[r] + sZq[ri] + EPSF;
        const float invz = 1.f / z;
#pragma unroll
        for (int ct = 0; ct < 4; ++ct)
            out[gbase + ri * LSTRIDE + 16 * ct + nn] = o[ct][r] * invz;
    }
}

// ---------------------------------------------------------------------------
// Fallback (tiny ws): fully sequential per-sequence scan, fp32, no workspace.
// ---------------------------------------------------------------------------
__global__ __launch_bounds__(64) void k_seq(const float* __restrict__ qin,
                                            const float* __restrict__ kin,
                                            const float* __restrict__ vin,
                                            float* __restrict__ out) {
    const int seq = blockIdx.x;
    const int n = seq / NHEAD, h = seq % NHEAD;
    const int lane = threadIdx.x;
    float Scol[DDIM];
#pragma unroll
    for (int d = 0; d < DDIM; ++d) Scol[d] = 0.0f;
    float kc = 0.0f;
    __shared__ float qk[2 * DDIM];
    int base = (n * LSEQ * NHEAD + h) * DDIM + lane;
    for (int i = 0; i < LSEQ; ++i) {
        float qval = phi(qin[base]);
        float kval = phi(kin[base]);
        float vval = vin[base];
        kc += kval;
        float zp = qval * kc;
#pragma unroll
        for (int off = 32; off > 0; off >>= 1) zp += __shfl_xor(zp, off, 64);
        float z = zp + EPSF;
        qk[2 * lane] = kval;
        qk[2 * lane + 1] = qval;
        __syncthreads();
        const float4* qk4 = (const float4*)qk;
        float acc = 0.0f;
#pragma unroll
        for (int d2 = 0; d2 < DDIM / 2; ++d2) {
            float4 t0 = qk4[d2];
            int d = 2 * d2;
            Scol[d]     += t0.x * vval;  acc += t0.y * Scol[d];
            Scol[d + 1] += t0.z * vval;  acc += t0.w * Scol[d + 1];
        }
        out[base] = acc / z;
        base += LSTRIDE;
        __syncthreads();
    }
}

// ---------------------------------------------------------------------------
extern "C" void kernel_launch(void* const* d_in, const int* in_sizes, int n_in,
                              void* d_out, int out_size, void* d_ws, size_t ws_size,
                              hipStream_t stream) {
    const float* q = (const float*)d_in[0];
    const float* k = (const float*)d_in[1];
    const float* v = (const float*)d_in[2];
    float* out = (float*)d_out;

    const size_t kv_shorts = (size_t)NH * NUMC * 4096;   // chunk sums, bf16
    const size_t gp_shorts = (size_t)NH * NGRP * 4096;   // group prefixes, bf16
    const size_t ks_floats = (size_t)NH * NUMC * 64;     // chunk ksums
    const size_t gk_floats = (size_t)NH * NGRP * 64;     // group ksum prefixes
    const size_t need = (kv_shorts + gp_shorts) * 2 + (ks_floats + gk_floats) * 4;

    if (ws_size >= need) {
        unsigned short* kv16 = (unsigned short*)d_ws;
        unsigned short* gp16 = kv16 + kv_shorts;
        float* ksum  = (float*)(gp16 + gp_shorts);
        float* gksum = ksum + ks_floats;
        k_sum_mf<<<NH * NUMC, 256, 0, stream>>>(k, v, kv16, ksum);
        k_gscan<<<NH * 16, 64, 0, stream>>>(kv16, gp16, ksum, gksum);
        k_out_mf<<<NH * NUMC, 256, 0, stream>>>(q, k, v, kv16, gp16, ksum, gksum, out);
    } else {
        k_seq<<<NH, 64, 0, stream>>>(q, k, v, out);
    }
}